// Round 1
// baseline (54.750 us; speedup 1.0000x reference)
//
#include <hip/hip_runtime.h>
#include <hip/hip_bf16.h>

typedef __attribute__((ext_vector_type(8))) short short8;
typedef __attribute__((ext_vector_type(16))) float f32x16;
typedef __attribute__((ext_vector_type(4))) float fx4;

#define LOG2E_F 1.4426950408889634f

// ws layout (ushort elements):
//   kb    [8000][8]  bf16                      @ elem 0       (128000 B)
//   cq    [8000][8]  bf16 (pre-scaled by log2e)@ elem 65536   (128000 B)
//   vfrag key-permuted B-fragment-ready tiles  @ elem 131072  (1024000 B)
// vfrag addressing for (key n, col j):
//   tile = n>>5, ks = (n>>4)&1, r = n&15, g = (r>>2)&1, e = (r&3) + 4*(r>>3)
//   elem = 131072 + tile*2048 + ks*1024 + g*512 + j*8 + e
// The (g,e) permutation is chosen so that the S^T MFMA output registers,
// packed in register order, form a valid PV A-fragment with NO cross-lane ops.

__device__ __forceinline__ float fast_exp2(float v) {
#if __has_builtin(__builtin_amdgcn_exp2f)
    return __builtin_amdgcn_exp2f(v);
#else
    return exp2f(v);
#endif
}

__device__ __forceinline__ short f2bf(float f) {
    return __builtin_bit_cast(short, __float2bfloat16(f));
}

// ---------------- Phase A: fused 1x1x1 projections ----------------
// One thread per (token n, output o); o<8 -> keys(Wb), o<16 -> queries(Wc, *log2e), else values(Wd).
__global__ __launch_bounds__(256, 1) void pam_proj(
    const float* __restrict__ x,
    const float* __restrict__ Wb,
    const float* __restrict__ Wc,
    const float* __restrict__ Wd,
    unsigned short* __restrict__ ws)
{
    unsigned idx = blockIdx.x * 256u + threadIdx.x;   // exactly 640000 threads
    unsigned n = idx / 80u;
    unsigned o = idx - n * 80u;

    const fx4* xr = reinterpret_cast<const fx4*>(x + (size_t)n * 64u);
    fx4 xv[16];
#pragma unroll
    for (int i = 0; i < 16; ++i) xv[i] = xr[i];

    const float* p;
    unsigned stride;
    float scale = 1.0f;
    if (o < 8u)        { p = Wb + o;         stride = 8u;  }
    else if (o < 16u)  { p = Wc + (o - 8u);  stride = 8u;  scale = LOG2E_F; }
    else               { p = Wd + (o - 16u); stride = 64u; }

    float acc = 0.0f;
#pragma unroll
    for (int c = 0; c < 16; ++c) {
        fx4 xc = xv[c];
        acc += xc[0] * p[0];
        acc += xc[1] * p[stride];
        acc += xc[2] * p[2u * stride];
        acc += xc[3] * p[3u * stride];
        p += 4u * stride;
    }
    acc *= scale;
    unsigned short hb = (unsigned short)f2bf(acc);

    if (o < 8u) {
        ws[n * 8u + o] = hb;
    } else if (o < 16u) {
        ws[65536u + n * 8u + (o - 8u)] = hb;
    } else {
        unsigned j  = o - 16u;
        unsigned t5 = n & 31u;
        unsigned ks = t5 >> 4;
        unsigned r  = t5 & 15u;
        unsigned g  = (r >> 2) & 1u;
        unsigned e  = (r & 3u) + ((r >> 3) << 2);
        ws[131072u + (n >> 5) * 2048u + ks * 1024u + g * 512u + j * 8u + e] = hb;
    }
}

// ---------------- Phase B: fused flash attention + epilogue ----------------
// 250 blocks x 256 thr. Block owns 32 queries; 4 waves split the 250 key-steps.
// Per step (32 keys): S^T = mfma(kb, cq) [dk=8 padded to 16 via zeroed upper-half
// frags]; e = exp2(st); lsum += e; pack e (reg order == A-frag thanks to the
// key-permuted vfrag layout); 4 PV mfmas. No max-tracking needed (|score|<~6).
__global__ __launch_bounds__(256, 1) void pam_attn(
    const float* __restrict__ x,
    const float* __restrict__ gamma_p,
    const unsigned short* __restrict__ ws,
    float* __restrict__ out)
{
    __shared__ float acc_s[4][32][64];   // per-wave partial ctx numerators
    __shared__ float ls_s[4][2][32];     // per-wave, per-half lsum partials

    const int tid  = threadIdx.x;
    const int wave = tid >> 6;
    const int lane = tid & 63;
    const int l31  = lane & 31;
    const int g    = lane >> 5;
    const int qbase = blockIdx.x * 32;

    const short8* kbp = reinterpret_cast<const short8*>(ws);
    const short8* cqp = reinterpret_cast<const short8*>(ws + 65536u);
    const short8* vp  = reinterpret_cast<const short8*>(ws + 131072u);

    // Persistent B-operand for S^T: cq rows (lanes 0-31), zeros above (d=8..15 pad).
    short8 cf = {};
    if (lane < 32) cf = cqp[qbase + l31];

    f32x16 acc0 = {};  // ctx cols  0..31 (jt=0)
    f32x16 acc1 = {};  // ctx cols 32..63 (jt=1)
    float ls0 = 0.f, ls1 = 0.f, ls2 = 0.f, ls3 = 0.f;

    const int s0 = (250 * wave) >> 2;
    const int s1 = (250 * (wave + 1)) >> 2;

    // one-step register prefetch
    short8 kf = {};
    if (lane < 32) kf = kbp[s0 * 32 + l31];
    int vb = s0 * 256 + g * 64 + l31;
    short8 v00 = vp[vb];         // ks=0, jt=0
    short8 v01 = vp[vb + 32];    // ks=0, jt=1
    short8 v10 = vp[vb + 128];   // ks=1, jt=0
    short8 v11 = vp[vb + 160];   // ks=1, jt=1

    for (int s = s0; s < s1; ++s) {
        const int sn = s + 1;
        short8 kfn = {};
        short8 n00 = {}, n01 = {}, n10 = {}, n11 = {};
        if (sn < s1) {                       // wave-uniform
            if (lane < 32) kfn = kbp[sn * 32 + l31];
            const int nb = sn * 256 + g * 64 + l31;
            n00 = vp[nb];
            n01 = vp[nb + 32];
            n10 = vp[nb + 128];
            n11 = vp[nb + 160];
        }

        f32x16 z = {};
        // S^T[key][q] * log2e ; rows=keys, cols=q
        f32x16 st = __builtin_amdgcn_mfma_f32_32x32x16_bf16(kf, cf, z, 0, 0, 0);

        float e[16];
#pragma unroll
        for (int r = 0; r < 16; ++r) e[r] = fast_exp2(st[r]);

        ls0 += (e[0]  + e[1])  + (e[2]  + e[3]);
        ls1 += (e[4]  + e[5])  + (e[6]  + e[7]);
        ls2 += (e[8]  + e[9])  + (e[10] + e[11]);
        ls3 += (e[12] + e[13]) + (e[14] + e[15]);

        // reg-order pack == PV A-fragment (vfrag key permutation absorbs transpose)
        short8 af0, af1;
#pragma unroll
        for (int r = 0; r < 8; ++r) af0[r] = f2bf(e[r]);
#pragma unroll
        for (int r = 0; r < 8; ++r) af1[r] = f2bf(e[8 + r]);

        acc0 = __builtin_amdgcn_mfma_f32_32x32x16_bf16(af0, v00, acc0, 0, 0, 0);
        acc1 = __builtin_amdgcn_mfma_f32_32x32x16_bf16(af0, v01, acc1, 0, 0, 0);
        acc0 = __builtin_amdgcn_mfma_f32_32x32x16_bf16(af1, v10, acc0, 0, 0, 0);
        acc1 = __builtin_amdgcn_mfma_f32_32x32x16_bf16(af1, v11, acc1, 0, 0, 0);

        kf = kfn; v00 = n00; v01 = n01; v10 = n10; v11 = n11;
    }

    // deterministic merge: each (wave,row,col) slot written by exactly one lane
    ls_s[wave][g][l31] = (ls0 + ls1) + (ls2 + ls3);
#pragma unroll
    for (int r = 0; r < 16; ++r) {
        const int row = (r & 3) + 8 * (r >> 2) + 4 * g;   // D-layout row = q
        acc_s[wave][row][l31]      = acc0[r];
        acc_s[wave][row][32 + l31] = acc1[r];
    }
    __syncthreads();

    // epilogue: out = gamma * acc/lsum + x   (f32 exact residual)
    const float gma = gamma_p[0];
    const int q  = tid >> 3;
    const int j0 = (tid & 7) * 8;
    float lq = 0.f;
#pragma unroll
    for (int w = 0; w < 4; ++w) lq += ls_s[w][0][q] + ls_s[w][1][q];
    const float inv = 1.0f / lq;

    const int base = (qbase + q) * 64 + j0;
#pragma unroll
    for (int c = 0; c < 2; ++c) {
        fx4 a = {};
#pragma unroll
        for (int w = 0; w < 4; ++w) {
            const fx4 t = *reinterpret_cast<const fx4*>(&acc_s[w][q][j0 + 4 * c]);
            a += t;
        }
        const fx4 xr = *reinterpret_cast<const fx4*>(x + base + 4 * c);
        fx4 o4 = a * (gma * inv) + xr;
        *reinterpret_cast<fx4*>(out + base + 4 * c) = o4;
    }
}

extern "C" void kernel_launch(void* const* d_in, const int* in_sizes, int n_in,
                              void* d_out, int out_size, void* d_ws, size_t ws_size,
                              hipStream_t stream)
{
    const float* x     = (const float*)d_in[0];
    const float* Wb    = (const float*)d_in[1];
    const float* Wc    = (const float*)d_in[2];
    const float* Wd    = (const float*)d_in[3];
    const float* gamma = (const float*)d_in[4];
    float* outp = (float*)d_out;
    unsigned short* ws = (unsigned short*)d_ws;

    hipLaunchKernelGGL(pam_proj, dim3(2500), dim3(256), 0, stream, x, Wb, Wc, Wd, ws);
    hipLaunchKernelGGL(pam_attn, dim3(250), dim3(256), 0, stream,
                       x, gamma, (const unsigned short*)ws, outp);
}

// Round 3
// 35.525 us; speedup vs baseline: 1.5412x; 1.5412x over previous
//
#include <hip/hip_runtime.h>
#include <hip/hip_bf16.h>

typedef __attribute__((ext_vector_type(8))) short short8;
typedef __attribute__((ext_vector_type(16))) float f32x16;
typedef __attribute__((ext_vector_type(4))) float fx4;
typedef __attribute__((ext_vector_type(4))) unsigned uint4v;

#define LOG2E_F 1.4426950408889634f

// ws ushort layout:
//   kb    [8000][8]  bf16                       @ elem 0
//   cq    [8000][8]  bf16 (pre-scaled by log2e) @ elem 65536
//   vfrag key-permuted B-fragment-ready tiles   @ elem 131072 (512000 elems)
// ws float layout (starts at byte 2 MiB, past the ushort region):
//   pacc  [1000][32][64] f32 block partial numerators @ f32 elem 524288
//   pls   [1000][32]     f32 block partial lsums      @ f32 elem 2621440
#define KB_OFF   0u
#define CQ_OFF   65536u
#define VF_OFF   131072u
#define PACC_F   524288u
#define PLS_F    2621440u

__device__ __forceinline__ float fast_exp2(float v) {
#if __has_builtin(__builtin_amdgcn_exp2f)
    return __builtin_amdgcn_exp2f(v);
#else
    return exp2f(v);
#endif
}

__device__ __forceinline__ unsigned short f2bfu(float f) {
    unsigned short u;
    __hip_bfloat16 h = __float2bfloat16(f);
    __builtin_memcpy(&u, &h, 2);
    return u;
}

// pack two f32 -> one u32 of 2 bf16 (compiler fuses the scalar casts into
// v_cvt_pk_bf16_f32; per learn_hip m240 do NOT hand-write the asm)
__device__ __forceinline__ unsigned pk2(float lo, float hi) {
    return (unsigned)f2bfu(lo) | ((unsigned)f2bfu(hi) << 16);
}

__device__ __forceinline__ short8 cvt8(fx4 a, fx4 b) {
    uint4v u;
    u[0] = pk2(a[0], a[1]);
    u[1] = pk2(a[2], a[3]);
    u[2] = pk2(b[0], b[1]);
    u[3] = pk2(b[2], b[3]);
    return __builtin_bit_cast(short8, u);
}

// ---------------- Phase A: MFMA projections ----------------
// C[8000x96] = X[8000x64] @ Wcomb[64x96]; cols 0-7 -> kb, 8-15 -> cq (Wc
// pre-scaled by log2e), 16-79 -> vfrag (key-permuted), 80-95 -> discarded.
// 63 blocks x 4 waves; wave owns 32 rows; K=64 -> 4 mfma per 32-col tile.
__global__ __launch_bounds__(256, 1) void pam_proj(
    const float* __restrict__ x,
    const float* __restrict__ Wb,
    const float* __restrict__ Wc,
    const float* __restrict__ Wd,
    unsigned short* __restrict__ ws)
{
    __shared__ alignas(16) unsigned short Wt[96][72];   // [col][k], padded stride

    const int tid = threadIdx.x;
#pragma unroll
    for (int i = 0; i < 24; ++i) {
        int e = tid + 256 * i;            // 0..6143
        int col = e >> 6, k = e & 63;
        float w;
        if (col < 8)       w = Wb[k * 8 + col];
        else if (col < 16) w = Wc[k * 8 + (col - 8)] * LOG2E_F;
        else if (col < 80) w = Wd[k * 64 + (col - 16)];
        else               w = 0.0f;
        Wt[col][k] = f2bfu(w);
    }
    __syncthreads();

    const int wave = tid >> 6, lane = tid & 63;
    const int l31 = lane & 31, g = lane >> 5;
    const int rowbase = blockIdx.x * 128 + wave * 32;
    if (rowbase >= 8000) return;          // no further barriers below

    // B frags from LDS: col = ct*32 + l31, k = kk*16 + g*8 + e
    short8 bfrag[3][4];
#pragma unroll
    for (int ct = 0; ct < 3; ++ct)
#pragma unroll
        for (int kk = 0; kk < 4; ++kk)
            bfrag[ct][kk] = *reinterpret_cast<const short8*>(&Wt[ct * 32 + l31][kk * 16 + g * 8]);

    // A frags from x: row = rowbase + l31, k = kk*16 + g*8 + e
    const float* xr = x + (size_t)(rowbase + l31) * 64 + g * 8;
    short8 afrag[4];
#pragma unroll
    for (int kk = 0; kk < 4; ++kk) {
        fx4 a = *reinterpret_cast<const fx4*>(xr + kk * 16);
        fx4 b = *reinterpret_cast<const fx4*>(xr + kk * 16 + 4);
        afrag[kk] = cvt8(a, b);
    }

    f32x16 acc[3] = {};
#pragma unroll
    for (int kk = 0; kk < 4; ++kk) {
#pragma unroll
        for (int ct = 0; ct < 3; ++ct)
            acc[ct] = __builtin_amdgcn_mfma_f32_32x32x16_bf16(afrag[kk], bfrag[ct][kk], acc[ct], 0, 0, 0);
    }

#pragma unroll
    for (int ct = 0; ct < 3; ++ct) {
        const int col = ct * 32 + l31;
#pragma unroll
        for (int r = 0; r < 16; ++r) {
            const int row = rowbase + (r & 3) + 8 * (r >> 2) + 4 * g;
            const unsigned short hv = f2bfu(acc[ct][r]);
            if (col < 8) {
                ws[KB_OFF + row * 8u + col] = hv;
            } else if (col < 16) {
                ws[CQ_OFF + row * 8u + (col - 8)] = hv;
            } else if (col < 80) {
                const unsigned j  = col - 16;
                const unsigned t5 = row & 31u;
                const unsigned ks = t5 >> 4;
                const unsigned rr = t5 & 15u;
                const unsigned gg = (rr >> 2) & 1u;
                const unsigned ee = (rr & 3u) + ((rr >> 3) << 2);
                ws[VF_OFF + (row >> 5) * 2048u + ks * 1024u + gg * 512u + j * 8u + ee] = hv;
            }
        }
    }
}

// ---------------- Phase B: flash attention, 4-way key split ----------------
// 1000 blocks x 256 thr. block = (q-tile qt = bid>>2) x (key part kp = bid&3).
// 4 waves split the part's ~62 steps; block writes f32 partial (acc, lsum).
__global__ __launch_bounds__(256, 4) void pam_attn(
    const unsigned short* __restrict__ ws,
    float* __restrict__ wsf)
{
    __shared__ alignas(16) float acc_s[4][32][64];
    __shared__ float ls_s[4][2][32];

    const int tid  = threadIdx.x;
    const int wave = tid >> 6;
    const int lane = tid & 63;
    const int l31  = lane & 31;
    const int g    = lane >> 5;
    const int qt   = blockIdx.x >> 2;
    const int kp   = blockIdx.x & 3;
    const int qbase = qt * 32;

    const short8* kbp = reinterpret_cast<const short8*>(ws + KB_OFF);
    const short8* cqp = reinterpret_cast<const short8*>(ws + CQ_OFF);
    const short8* vp  = reinterpret_cast<const short8*>(ws + VF_OFF);

    short8 cf = {};
    if (lane < 32) cf = cqp[qbase + l31];

    f32x16 acc0 = {};
    f32x16 acc1 = {};
    float ls0 = 0.f, ls1 = 0.f, ls2 = 0.f, ls3 = 0.f;

    const int plen   = (kp < 2) ? 63 : 62;
    const int pstart = kp * 62 + ((kp < 2) ? kp : 2);
    const int s0 = pstart + (plen * wave) / 4;
    const int s1 = pstart + (plen * (wave + 1)) / 4;

    // one-step register prefetch
    short8 kf = {};
    if (lane < 32) kf = kbp[s0 * 32 + l31];
    const int vb = s0 * 256 + g * 64 + l31;
    short8 v00 = vp[vb];
    short8 v01 = vp[vb + 32];
    short8 v10 = vp[vb + 128];
    short8 v11 = vp[vb + 160];

    for (int s = s0; s < s1; ++s) {
        const int sn = s + 1;
        short8 kfn = {};
        short8 n00 = {}, n01 = {}, n10 = {}, n11 = {};
        if (sn < s1) {
            if (lane < 32) kfn = kbp[sn * 32 + l31];
            const int nb = sn * 256 + g * 64 + l31;
            n00 = vp[nb];
            n01 = vp[nb + 32];
            n10 = vp[nb + 128];
            n11 = vp[nb + 160];
        }

        f32x16 z = {};
        f32x16 st = __builtin_amdgcn_mfma_f32_32x32x16_bf16(kf, cf, z, 0, 0, 0);

        float e[16];
#pragma unroll
        for (int r = 0; r < 16; ++r) e[r] = fast_exp2(st[r]);

        ls0 += (e[0]  + e[1])  + (e[2]  + e[3]);
        ls1 += (e[4]  + e[5])  + (e[6]  + e[7]);
        ls2 += (e[8]  + e[9])  + (e[10] + e[11]);
        ls3 += (e[12] + e[13]) + (e[14] + e[15]);

        uint4v u0, u1;
#pragma unroll
        for (int p = 0; p < 4; ++p) u0[p] = pk2(e[2 * p], e[2 * p + 1]);
#pragma unroll
        for (int p = 0; p < 4; ++p) u1[p] = pk2(e[8 + 2 * p], e[9 + 2 * p]);
        const short8 af0 = __builtin_bit_cast(short8, u0);
        const short8 af1 = __builtin_bit_cast(short8, u1);

        acc0 = __builtin_amdgcn_mfma_f32_32x32x16_bf16(af0, v00, acc0, 0, 0, 0);
        acc1 = __builtin_amdgcn_mfma_f32_32x32x16_bf16(af0, v01, acc1, 0, 0, 0);
        acc0 = __builtin_amdgcn_mfma_f32_32x32x16_bf16(af1, v10, acc0, 0, 0, 0);
        acc1 = __builtin_amdgcn_mfma_f32_32x32x16_bf16(af1, v11, acc1, 0, 0, 0);

        kf = kfn; v00 = n00; v01 = n01; v10 = n10; v11 = n11;
    }

    ls_s[wave][g][l31] = (ls0 + ls1) + (ls2 + ls3);
#pragma unroll
    for (int r = 0; r < 16; ++r) {
        const int row = (r & 3) + 8 * (r >> 2) + 4 * g;
        acc_s[wave][row][l31]      = acc0[r];
        acc_s[wave][row][32 + l31] = acc1[r];
    }
    __syncthreads();

    // deterministic block-partial write
    if (tid < 32) {
        float s = 0.f;
#pragma unroll
        for (int w = 0; w < 4; ++w) s += ls_s[w][0][tid] + ls_s[w][1][tid];
        wsf[PLS_F + blockIdx.x * 32u + tid] = s;
    }
    const int q = tid >> 3, j0 = (tid & 7) * 8;
    fx4 a0 = {}, a1 = {};
#pragma unroll
    for (int w = 0; w < 4; ++w) {
        a0 += *reinterpret_cast<const fx4*>(&acc_s[w][q][j0]);
        a1 += *reinterpret_cast<const fx4*>(&acc_s[w][q][j0 + 4]);
    }
    float* pb = wsf + PACC_F + (size_t)blockIdx.x * 2048u + q * 64 + j0;
    *reinterpret_cast<fx4*>(pb)     = a0;
    *reinterpret_cast<fx4*>(pb + 4) = a1;
}

// ---------------- Phase C: merge 4 partials + epilogue ----------------
__global__ __launch_bounds__(256) void pam_merge(
    const float* __restrict__ x,
    const float* __restrict__ gamma_p,
    const float* __restrict__ wsf,
    float* __restrict__ out)
{
    const int tid = threadIdx.x;
    const int qt  = blockIdx.x;
    const int q = tid >> 3, j0 = (tid & 7) * 8;

    float lq = 0.f;
#pragma unroll
    for (int p = 0; p < 4; ++p) lq += wsf[PLS_F + (qt * 4 + p) * 32u + q];
    const float sc = gamma_p[0] / lq;

    fx4 a0 = {}, a1 = {};
#pragma unroll
    for (int p = 0; p < 4; ++p) {
        const float* pb = wsf + PACC_F + (size_t)(qt * 4 + p) * 2048u + q * 64 + j0;
        a0 += *reinterpret_cast<const fx4*>(pb);
        a1 += *reinterpret_cast<const fx4*>(pb + 4);
    }

    const int base = (qt * 32 + q) * 64 + j0;
    const fx4 x0 = *reinterpret_cast<const fx4*>(x + base);
    const fx4 x1 = *reinterpret_cast<const fx4*>(x + base + 4);
    *reinterpret_cast<fx4*>(out + base)     = a0 * sc + x0;
    *reinterpret_cast<fx4*>(out + base + 4) = a1 * sc + x1;
}

extern "C" void kernel_launch(void* const* d_in, const int* in_sizes, int n_in,
                              void* d_out, int out_size, void* d_ws, size_t ws_size,
                              hipStream_t stream)
{
    const float* x     = (const float*)d_in[0];
    const float* Wb    = (const float*)d_in[1];
    const float* Wc    = (const float*)d_in[2];
    const float* Wd    = (const float*)d_in[3];
    const float* gamma = (const float*)d_in[4];
    float* outp = (float*)d_out;
    unsigned short* ws = (unsigned short*)d_ws;
    float* wsf = (float*)d_ws;

    hipLaunchKernelGGL(pam_proj, dim3(63), dim3(256), 0, stream, x, Wb, Wc, Wd, ws);
    hipLaunchKernelGGL(pam_attn, dim3(1000), dim3(256), 0, stream,
                       (const unsigned short*)ws, wsf);
    hipLaunchKernelGGL(pam_merge, dim3(250), dim3(256), 0, stream,
                       x, gamma, (const float*)wsf, outp);
}